// Round 1
// baseline (514.411 us; speedup 1.0000x reference)
//
#include <hip/hip_runtime.h>
#include <math.h>

// ---------------------------------------------------------------------------
// GCN 3-layer: per layer  h = X @ W ;  out[d] = dis[d]*sum_{e:dst=d} dis[src]*h[src]
//                                             + dis[d]^2*h[d] + b ; relu (layers 1,2)
// CSR-by-dst built on device each call (deterministic work).
// ---------------------------------------------------------------------------

__global__ void zero_ints(int* __restrict__ a, int n) {
    int i = blockIdx.x * blockDim.x + threadIdx.x;
    int st = gridDim.x * blockDim.x;
    for (; i < n; i += st) a[i] = 0;
}

__global__ void count_kernel(const int* __restrict__ dst, int* __restrict__ counts, int E) {
    int i = blockIdx.x * blockDim.x + threadIdx.x;
    int st = gridDim.x * blockDim.x;
    for (; i < E; i += st) atomicAdd(&counts[dst[i]], 1);
}

__global__ void dis_kernel(const int* __restrict__ counts, float* __restrict__ dis, int n) {
    int i = blockIdx.x * blockDim.x + threadIdx.x;
    int st = gridDim.x * blockDim.x;
    for (; i < n; i += st) {
        float deg = (float)(counts[i] + 1);   // +1 self-loop
        dis[i] = rsqrtf(deg);
    }
}

// single-block sequential-tile exclusive scan; offs has n+1 entries
__global__ __launch_bounds__(1024) void scan_kernel(const int* __restrict__ counts,
                                                    int* __restrict__ offs, int n) {
    __shared__ int sm[1024];
    __shared__ int carry_s;
    const int t = threadIdx.x;
    if (t == 0) carry_s = 0;
    __syncthreads();
    const int ntiles = (n + 1023) / 1024;
    for (int tile = 0; tile < ntiles; ++tile) {
        const int idx = tile * 1024 + t;
        const int carry = carry_s;
        int v = (idx < n) ? counts[idx] : 0;
        sm[t] = v;
        __syncthreads();
        for (int off = 1; off < 1024; off <<= 1) {
            int x = (t >= off) ? sm[t - off] : 0;
            __syncthreads();
            sm[t] += x;
            __syncthreads();
        }
        int incl = sm[t];
        if (idx < n) offs[idx] = carry + incl - v;   // exclusive
        __syncthreads();
        if (t == 0) carry_s = carry + sm[1023];
        __syncthreads();
    }
    if (t == 0) offs[n] = carry_s;
}

__global__ void fill_kernel(const int* __restrict__ src, const int* __restrict__ dst,
                            const float* __restrict__ dis, const int* __restrict__ offs,
                            int* __restrict__ cursor, int* __restrict__ csr_src,
                            float* __restrict__ csr_w, int E) {
    int i = blockIdx.x * blockDim.x + threadIdx.x;
    int st = gridDim.x * blockDim.x;
    for (; i < E; i += st) {
        int d = dst[i];
        int s = src[i];
        int p = offs[d] + atomicAdd(&cursor[d], 1);
        csr_src[p] = s;
        csr_w[p] = dis[s];
    }
}

// ---------------------------------------------------------------------------
// GEMM: Y[r][c] = sum_k X[r][k] * W[k][c];  K = 128 fixed; NOUT in {128, 64}.
// BM = 32 rows/block, 256 threads, W fully staged in LDS, X tile in LDS.
// ---------------------------------------------------------------------------
template <int NOUT>
__global__ __launch_bounds__(256) void gemm_kernel(const float* __restrict__ X,
                                                   const float* __restrict__ W,
                                                   float* __restrict__ Y, int nrows) {
    __shared__ float Ws[128 * NOUT];
    __shared__ float Xs[32 * 128];
    const int t = threadIdx.x;

    // stage W (128*NOUT floats)
    {
        const float4* W4 = (const float4*)W;
        float4* Ws4 = (float4*)Ws;
        constexpr int WV = 128 * NOUT / 4;
        for (int i = t; i < WV; i += 256) Ws4[i] = W4[i];
    }
    // stage X tile (32 x 128)
    const int row0 = blockIdx.x * 32;
    {
        float4* Xs4 = (float4*)Xs;
        const float4* X4 = (const float4*)X;
        for (int i = t; i < 32 * 128 / 4; i += 256) {
            int r = i >> 5;            // 32 float4 per row
            int rr = row0 + r;
            float4 v = make_float4(0.f, 0.f, 0.f, 0.f);
            if (rr < nrows) v = X4[(size_t)rr * 32 + (i & 31)];
            Xs4[i] = v;
        }
    }
    __syncthreads();

    constexpr int CPT = NOUT / 32;     // cols per thread: 4 (128) or 2 (64)
    const int tr = t >> 5;             // 0..7, 4 rows each
    const int tcv = t & 31;            // vector col index

    float acc[4][CPT];
#pragma unroll
    for (int i = 0; i < 4; ++i)
#pragma unroll
        for (int j = 0; j < CPT; ++j) acc[i][j] = 0.f;

    const float4* Xs4 = (const float4*)Xs;

    for (int k = 0; k < 128; k += 4) {
        float4 a[4];
#pragma unroll
        for (int i = 0; i < 4; ++i) a[i] = Xs4[(size_t)(tr * 4 + i) * 32 + (k >> 2)];
#pragma unroll
        for (int kk = 0; kk < 4; ++kk) {
            if constexpr (CPT == 4) {
                float4 b = ((const float4*)Ws)[(size_t)(k + kk) * 32 + tcv];
#pragma unroll
                for (int i = 0; i < 4; ++i) {
                    float av = reinterpret_cast<const float*>(&a[i])[kk];
                    acc[i][0] = fmaf(av, b.x, acc[i][0]);
                    acc[i][1] = fmaf(av, b.y, acc[i][1]);
                    acc[i][2] = fmaf(av, b.z, acc[i][2]);
                    acc[i][3] = fmaf(av, b.w, acc[i][3]);
                }
            } else {
                float2 b = ((const float2*)Ws)[(size_t)(k + kk) * 32 + tcv];
#pragma unroll
                for (int i = 0; i < 4; ++i) {
                    float av = reinterpret_cast<const float*>(&a[i])[kk];
                    acc[i][0] = fmaf(av, b.x, acc[i][0]);
                    acc[i][1] = fmaf(av, b.y, acc[i][1]);
                }
            }
        }
    }

#pragma unroll
    for (int i = 0; i < 4; ++i) {
        int row = row0 + tr * 4 + i;
        if (row < nrows) {
            if constexpr (CPT == 4) {
                float4 v = make_float4(acc[i][0], acc[i][1], acc[i][2], acc[i][3]);
                ((float4*)Y)[(size_t)row * (NOUT / 4) + tcv] = v;
            } else {
                float2 v = make_float2(acc[i][0], acc[i][1]);
                ((float2*)Y)[(size_t)row * (NOUT / 2) + tcv] = v;
            }
        }
    }
}

// ---------------------------------------------------------------------------
// Aggregation: one block per node, F threads (one per feature).
// out[d][f] = dis[d]*sum_i w_i*h[s_i][f] + dis[d]^2*h[d][f] + bias[f]
// ---------------------------------------------------------------------------
template <int F, bool RELU>
__global__ __launch_bounds__(F) void agg_kernel(const float* __restrict__ h,
                                                const float* __restrict__ dis,
                                                const int* __restrict__ offs,
                                                const int* __restrict__ csr_src,
                                                const float* __restrict__ csr_w,
                                                const float* __restrict__ bias,
                                                float* __restrict__ out) {
    const int d = blockIdx.x;
    const int f = threadIdx.x;
    const int beg = offs[d];
    const int end = offs[d + 1];
    float acc = 0.f;
    for (int i = beg; i < end; ++i) {
        int s = csr_src[i];
        float w = csr_w[i];
        acc = fmaf(w, h[(size_t)s * F + f], acc);
    }
    float dd = dis[d];
    float r = fmaf(dd, acc, dd * dd * h[(size_t)d * F + f]) + bias[f];
    if (RELU) r = fmaxf(r, 0.f);
    out[(size_t)d * F + f] = r;
}

// ---------------------------------------------------------------------------

extern "C" void kernel_launch(void* const* d_in, const int* in_sizes, int n_in,
                              void* d_out, int out_size, void* d_ws, size_t ws_size,
                              hipStream_t stream) {
    const float* x  = (const float*)d_in[0];
    const int*   ei = (const int*)d_in[1];
    const float* W1 = (const float*)d_in[2];
    const float* b1 = (const float*)d_in[3];
    const float* W2 = (const float*)d_in[4];
    const float* b2 = (const float*)d_in[5];
    const float* W3 = (const float*)d_in[6];
    const float* b3 = (const float*)d_in[7];

    const int N = in_sizes[0] / 128;
    const int E = in_sizes[1] / 2;
    const int* src = ei;
    const int* dst = ei + E;
    float* out = (float*)d_out;

    char* w = (char*)d_ws;
    auto take = [&](size_t bytes) -> void* {
        void* p = (void*)w;
        w += (bytes + 255) & ~(size_t)255;
        return p;
    };
    int*   counts = (int*)take((size_t)N * 4);
    int*   offs   = (int*)take((size_t)(N + 1) * 4);
    int*   cursor = (int*)take((size_t)N * 4);
    float* dis    = (float*)take((size_t)N * 4);
    int*   csr_s  = (int*)take((size_t)E * 4);
    float* csr_w  = (float*)take((size_t)E * 4);
    float* G      = (float*)take((size_t)N * 128 * 4);
    float* H      = (float*)take((size_t)N * 128 * 4);

    // --- graph preprocessing (cheap, rebuilt every call) ---
    zero_ints<<<512, 256, 0, stream>>>(counts, N);
    zero_ints<<<512, 256, 0, stream>>>(cursor, N);
    count_kernel<<<2048, 256, 0, stream>>>(dst, counts, E);
    dis_kernel<<<(N + 255) / 256, 256, 0, stream>>>(counts, dis, N);
    scan_kernel<<<1, 1024, 0, stream>>>(counts, offs, N);
    fill_kernel<<<2048, 256, 0, stream>>>(src, dst, dis, offs, cursor, csr_s, csr_w, E);

    const int gblocks = (N + 31) / 32;

    // layer 1
    gemm_kernel<128><<<gblocks, 256, 0, stream>>>(x, W1, G, N);
    agg_kernel<128, true><<<N, 128, 0, stream>>>(G, dis, offs, csr_s, csr_w, b1, H);
    // layer 2
    gemm_kernel<128><<<gblocks, 256, 0, stream>>>(H, W2, G, N);
    agg_kernel<128, true><<<N, 128, 0, stream>>>(G, dis, offs, csr_s, csr_w, b2, H);
    // layer 3 (project to 64 first, then aggregate on 64 dims)
    gemm_kernel<64><<<gblocks, 256, 0, stream>>>(H, W3, G, N);
    agg_kernel<64, false><<<N, 64, 0, stream>>>(G, dis, offs, csr_s, csr_w, b3, out);
}

// Round 2
// 338.645 us; speedup vs baseline: 1.5190x; 1.5190x over previous
//
#include <hip/hip_runtime.h>
#include <math.h>

// ---------------------------------------------------------------------------
// GCN 3-layer: per layer  h = X @ W ;  out[d] = dis[d]*sum_{e:dst=d} dis[src]*h[src]
//                                             + dis[d]^2*h[d] + b ; relu (layers 1,2)
// CSR-by-dst built on device each call (deterministic work).
// ---------------------------------------------------------------------------

__global__ void zero_ints(int* __restrict__ a, int n) {
    int i = blockIdx.x * blockDim.x + threadIdx.x;
    int st = gridDim.x * blockDim.x;
    for (; i < n; i += st) a[i] = 0;
}

__global__ void count_kernel(const int* __restrict__ dst, int* __restrict__ counts, int E) {
    int i = blockIdx.x * blockDim.x + threadIdx.x;
    int st = gridDim.x * blockDim.x;
    for (; i < E; i += st) atomicAdd(&counts[dst[i]], 1);
}

__global__ void dis_kernel(const int* __restrict__ counts, float* __restrict__ dis, int n) {
    int i = blockIdx.x * blockDim.x + threadIdx.x;
    int st = gridDim.x * blockDim.x;
    for (; i < n; i += st) {
        float deg = (float)(counts[i] + 1);   // +1 self-loop
        dis[i] = rsqrtf(deg);
    }
}

// --------------------------- multi-block scan ------------------------------
// grid = NBLK = ceil((n+1)/256); chunk of 256 per block.
__global__ __launch_bounds__(256) void block_sum_kernel(const int* __restrict__ counts,
                                                        int* __restrict__ bsum, int n) {
    const int b = blockIdx.x;
    const int t = threadIdx.x;
    const int idx = b * 256 + t;
    int v = (idx < n) ? counts[idx] : 0;
#pragma unroll
    for (int o = 32; o > 0; o >>= 1) v += __shfl_down(v, o, 64);
    __shared__ int ws[4];
    if ((t & 63) == 0) ws[t >> 6] = v;
    __syncthreads();
    if (t == 0) bsum[b] = ws[0] + ws[1] + ws[2] + ws[3];
}

// single block, exclusive scan of bsum[nb] in place (nb <= 256)
__global__ __launch_bounds__(256) void small_scan_kernel(int* __restrict__ bsum, int nb) {
    __shared__ int sm[256];
    const int t = threadIdx.x;
    int v = (t < nb) ? bsum[t] : 0;
    sm[t] = v;
    __syncthreads();
    for (int o = 1; o < 256; o <<= 1) {
        int x = (t >= o) ? sm[t - o] : 0;
        __syncthreads();
        sm[t] += x;
        __syncthreads();
    }
    if (t < nb) bsum[t] = sm[t] - v;   // exclusive
}

__global__ __launch_bounds__(256) void scan_block_kernel(const int* __restrict__ counts,
                                                         const int* __restrict__ bsum,
                                                         int* __restrict__ offs, int n, int E) {
    const int b = blockIdx.x;
    const int t = threadIdx.x;
    const int idx = b * 256 + t;
    int v = (idx < n) ? counts[idx] : 0;
    __shared__ int sm[256];
    sm[t] = v;
    __syncthreads();
    for (int o = 1; o < 256; o <<= 1) {
        int x = (t >= o) ? sm[t - o] : 0;
        __syncthreads();
        sm[t] += x;
        __syncthreads();
    }
    if (idx < n) offs[idx] = bsum[b] + sm[t] - v;   // exclusive prefix
    if (idx == n) offs[n] = E;
}

__global__ void fill_kernel(const int* __restrict__ src, const int* __restrict__ dst,
                            const float* __restrict__ dis, const int* __restrict__ offs,
                            int* __restrict__ cursor, int* __restrict__ csr_src,
                            float* __restrict__ csr_w, int E) {
    int i = blockIdx.x * blockDim.x + threadIdx.x;
    int st = gridDim.x * blockDim.x;
    for (; i < E; i += st) {
        int d = dst[i];
        int s = src[i];
        int p = offs[d] + atomicAdd(&cursor[d], 1);
        csr_src[p] = s;
        csr_w[p] = dis[s];
    }
}

// ---------------------------------------------------------------------------
// GEMM: Y[r][c] = sum_k X[r][k] * W[k][c];  K = 128 fixed; NOUT in {128, 64}.
// BM = 32 rows/block, 256 threads, W fully staged in LDS, X tile in LDS.
// ---------------------------------------------------------------------------
template <int NOUT>
__global__ __launch_bounds__(256) void gemm_kernel(const float* __restrict__ X,
                                                   const float* __restrict__ W,
                                                   float* __restrict__ Y, int nrows) {
    __shared__ float Ws[128 * NOUT];
    __shared__ float Xs[32 * 128];
    const int t = threadIdx.x;

    // stage W (128*NOUT floats)
    {
        const float4* W4 = (const float4*)W;
        float4* Ws4 = (float4*)Ws;
        constexpr int WV = 128 * NOUT / 4;
        for (int i = t; i < WV; i += 256) Ws4[i] = W4[i];
    }
    // stage X tile (32 x 128)
    const int row0 = blockIdx.x * 32;
    {
        float4* Xs4 = (float4*)Xs;
        const float4* X4 = (const float4*)X;
        for (int i = t; i < 32 * 128 / 4; i += 256) {
            int r = i >> 5;            // 32 float4 per row
            int rr = row0 + r;
            float4 v = make_float4(0.f, 0.f, 0.f, 0.f);
            if (rr < nrows) v = X4[(size_t)rr * 32 + (i & 31)];
            Xs4[i] = v;
        }
    }
    __syncthreads();

    constexpr int CPT = NOUT / 32;     // cols per thread: 4 (128) or 2 (64)
    const int tr = t >> 5;             // 0..7, 4 rows each
    const int tcv = t & 31;            // vector col index

    float acc[4][CPT];
#pragma unroll
    for (int i = 0; i < 4; ++i)
#pragma unroll
        for (int j = 0; j < CPT; ++j) acc[i][j] = 0.f;

    const float4* Xs4 = (const float4*)Xs;

    for (int k = 0; k < 128; k += 4) {
        float4 a[4];
#pragma unroll
        for (int i = 0; i < 4; ++i) a[i] = Xs4[(size_t)(tr * 4 + i) * 32 + (k >> 2)];
#pragma unroll
        for (int kk = 0; kk < 4; ++kk) {
            if constexpr (CPT == 4) {
                float4 b = ((const float4*)Ws)[(size_t)(k + kk) * 32 + tcv];
#pragma unroll
                for (int i = 0; i < 4; ++i) {
                    float av = reinterpret_cast<const float*>(&a[i])[kk];
                    acc[i][0] = fmaf(av, b.x, acc[i][0]);
                    acc[i][1] = fmaf(av, b.y, acc[i][1]);
                    acc[i][2] = fmaf(av, b.z, acc[i][2]);
                    acc[i][3] = fmaf(av, b.w, acc[i][3]);
                }
            } else {
                float2 b = ((const float2*)Ws)[(size_t)(k + kk) * 32 + tcv];
#pragma unroll
                for (int i = 0; i < 4; ++i) {
                    float av = reinterpret_cast<const float*>(&a[i])[kk];
                    acc[i][0] = fmaf(av, b.x, acc[i][0]);
                    acc[i][1] = fmaf(av, b.y, acc[i][1]);
                }
            }
        }
    }

#pragma unroll
    for (int i = 0; i < 4; ++i) {
        int row = row0 + tr * 4 + i;
        if (row < nrows) {
            if constexpr (CPT == 4) {
                float4 v = make_float4(acc[i][0], acc[i][1], acc[i][2], acc[i][3]);
                ((float4*)Y)[(size_t)row * (NOUT / 4) + tcv] = v;
            } else {
                float2 v = make_float2(acc[i][0], acc[i][1]);
                ((float2*)Y)[(size_t)row * (NOUT / 2) + tcv] = v;
            }
        }
    }
}

// ---------------------------------------------------------------------------
// Aggregation: one block per node, F threads (one per feature).
// out[d][f] = dis[d]*sum_i w_i*h[s_i][f] + dis[d]^2*h[d][f] + bias[f]
// Unrolled x4 with independent accumulators -> 4 outstanding row gathers.
// ---------------------------------------------------------------------------
template <int F, bool RELU>
__global__ __launch_bounds__(F) void agg_kernel(const float* __restrict__ h,
                                                const float* __restrict__ dis,
                                                const int* __restrict__ offs,
                                                const int* __restrict__ csr_src,
                                                const float* __restrict__ csr_w,
                                                const float* __restrict__ bias,
                                                float* __restrict__ out) {
    const int d = blockIdx.x;
    const int f = threadIdx.x;
    const int beg = offs[d];
    const int end = offs[d + 1];
    float a0 = 0.f, a1 = 0.f, a2 = 0.f, a3 = 0.f;
    int i = beg;
    const int n4 = beg + ((end - beg) & ~3);
    for (; i < n4; i += 4) {
        int s0 = csr_src[i];
        int s1 = csr_src[i + 1];
        int s2 = csr_src[i + 2];
        int s3 = csr_src[i + 3];
        float w0 = csr_w[i];
        float w1 = csr_w[i + 1];
        float w2 = csr_w[i + 2];
        float w3 = csr_w[i + 3];
        float v0 = h[(size_t)s0 * F + f];
        float v1 = h[(size_t)s1 * F + f];
        float v2 = h[(size_t)s2 * F + f];
        float v3 = h[(size_t)s3 * F + f];
        a0 = fmaf(w0, v0, a0);
        a1 = fmaf(w1, v1, a1);
        a2 = fmaf(w2, v2, a2);
        a3 = fmaf(w3, v3, a3);
    }
    for (; i < end; ++i) a0 = fmaf(csr_w[i], h[(size_t)csr_src[i] * F + f], a0);
    float acc = (a0 + a1) + (a2 + a3);
    float dd = dis[d];
    float r = fmaf(dd, acc, dd * dd * h[(size_t)d * F + f]) + bias[f];
    if (RELU) r = fmaxf(r, 0.f);
    out[(size_t)d * F + f] = r;
}

// ---------------------------------------------------------------------------

extern "C" void kernel_launch(void* const* d_in, const int* in_sizes, int n_in,
                              void* d_out, int out_size, void* d_ws, size_t ws_size,
                              hipStream_t stream) {
    const float* x  = (const float*)d_in[0];
    const int*   ei = (const int*)d_in[1];
    const float* W1 = (const float*)d_in[2];
    const float* b1 = (const float*)d_in[3];
    const float* W2 = (const float*)d_in[4];
    const float* b2 = (const float*)d_in[5];
    const float* W3 = (const float*)d_in[6];
    const float* b3 = (const float*)d_in[7];

    const int N = in_sizes[0] / 128;
    const int E = in_sizes[1] / 2;
    const int* src = ei;
    const int* dst = ei + E;
    float* out = (float*)d_out;

    char* w = (char*)d_ws;
    auto take = [&](size_t bytes) -> void* {
        void* p = (void*)w;
        w += (bytes + 255) & ~(size_t)255;
        return p;
    };
    // counts and cursor adjacent so one zero kernel covers both
    int*   counts = (int*)take((size_t)N * 4);
    int*   cursor = (int*)take((size_t)N * 4);   // note: 256B-aligned gap is fine (zeroed too)
    int*   offs   = (int*)take((size_t)(N + 1) * 4);
    float* dis    = (float*)take((size_t)N * 4);
    int*   bsum   = (int*)take((size_t)1024 * 4);
    int*   csr_s  = (int*)take((size_t)E * 4);
    float* csr_w  = (float*)take((size_t)E * 4);
    float* G      = (float*)take((size_t)N * 128 * 4);
    float* H      = (float*)take((size_t)N * 128 * 4);

    const int NBLK = (N + 256) / 256;   // covers idx up to N (for offs[N]=E write)

    // --- graph preprocessing (cheap, rebuilt every call) ---
    zero_ints<<<256, 256, 0, stream>>>(counts, (int)(((char*)offs - (char*)counts) / 4));
    count_kernel<<<2048, 256, 0, stream>>>(dst, counts, E);
    dis_kernel<<<(N + 255) / 256, 256, 0, stream>>>(counts, dis, N);
    block_sum_kernel<<<NBLK, 256, 0, stream>>>(counts, bsum, N);
    small_scan_kernel<<<1, 256, 0, stream>>>(bsum, NBLK);
    scan_block_kernel<<<NBLK, 256, 0, stream>>>(counts, bsum, offs, N, E);
    fill_kernel<<<2048, 256, 0, stream>>>(src, dst, dis, offs, cursor, csr_s, csr_w, E);

    const int gblocks = (N + 31) / 32;

    // layer 1
    gemm_kernel<128><<<gblocks, 256, 0, stream>>>(x, W1, G, N);
    agg_kernel<128, true><<<N, 128, 0, stream>>>(G, dis, offs, csr_s, csr_w, b1, H);
    // layer 2
    gemm_kernel<128><<<gblocks, 256, 0, stream>>>(H, W2, G, N);
    agg_kernel<128, true><<<N, 128, 0, stream>>>(G, dis, offs, csr_s, csr_w, b2, H);
    // layer 3 (project to 64 first, then aggregate on 64 dims)
    gemm_kernel<64><<<gblocks, 256, 0, stream>>>(H, W3, G, N);
    agg_kernel<64, false><<<N, 64, 0, stream>>>(G, dis, offs, csr_s, csr_w, b3, out);
}

// Round 4
// 329.959 us; speedup vs baseline: 1.5590x; 1.0263x over previous
//
#include <hip/hip_runtime.h>
#include <math.h>

// ---------------------------------------------------------------------------
// GCN 3-layer: per layer  h = X @ W ;  out[d] = dis[d]*sum_{e:dst=d} dis[src]*h[src]
//                                             + dis[d]^2*h[d] + b ; relu (layers 1,2)
// CSR-by-dst built on device each call. csr entry = int2{src, bits(dis[src])}.
// ---------------------------------------------------------------------------

__global__ void zero_ints(int* __restrict__ a, int n) {
    int i = blockIdx.x * blockDim.x + threadIdx.x;
    int st = gridDim.x * blockDim.x;
    for (; i < n; i += st) a[i] = 0;
}

// counts in-degree AND records each edge's rank within its dst bucket
__global__ void count_kernel(const int* __restrict__ dst, int* __restrict__ counts,
                             int* __restrict__ rank, int E) {
    int i = blockIdx.x * blockDim.x + threadIdx.x;
    int st = gridDim.x * blockDim.x;
    for (; i < E; i += st) rank[i] = atomicAdd(&counts[dst[i]], 1);
}

__global__ void dis_kernel(const int* __restrict__ counts, float* __restrict__ dis, int n) {
    int i = blockIdx.x * blockDim.x + threadIdx.x;
    int st = gridDim.x * blockDim.x;
    for (; i < n; i += st) {
        float deg = (float)(counts[i] + 1);   // +1 self-loop
        dis[i] = rsqrtf(deg);
    }
}

// --------------------------- multi-block scan ------------------------------
__global__ __launch_bounds__(256) void block_sum_kernel(const int* __restrict__ counts,
                                                        int* __restrict__ bsum, int n) {
    const int b = blockIdx.x;
    const int t = threadIdx.x;
    const int idx = b * 256 + t;
    int v = (idx < n) ? counts[idx] : 0;
#pragma unroll
    for (int o = 32; o > 0; o >>= 1) v += __shfl_down(v, o, 64);
    __shared__ int ws[4];
    if ((t & 63) == 0) ws[t >> 6] = v;
    __syncthreads();
    if (t == 0) bsum[b] = ws[0] + ws[1] + ws[2] + ws[3];
}

__global__ __launch_bounds__(256) void small_scan_kernel(int* __restrict__ bsum, int nb) {
    __shared__ int sm[256];
    const int t = threadIdx.x;
    int v = (t < nb) ? bsum[t] : 0;
    sm[t] = v;
    __syncthreads();
    for (int o = 1; o < 256; o <<= 1) {
        int x = (t >= o) ? sm[t - o] : 0;
        __syncthreads();
        sm[t] += x;
        __syncthreads();
    }
    if (t < nb) bsum[t] = sm[t] - v;   // exclusive
}

__global__ __launch_bounds__(256) void scan_block_kernel(const int* __restrict__ counts,
                                                         const int* __restrict__ bsum,
                                                         int* __restrict__ offs, int n, int E) {
    const int b = blockIdx.x;
    const int t = threadIdx.x;
    const int idx = b * 256 + t;
    int v = (idx < n) ? counts[idx] : 0;
    __shared__ int sm[256];
    sm[t] = v;
    __syncthreads();
    for (int o = 1; o < 256; o <<= 1) {
        int x = (t >= o) ? sm[t - o] : 0;
        __syncthreads();
        sm[t] += x;
        __syncthreads();
    }
    if (idx < n) offs[idx] = bsum[b] + sm[t] - v;   // exclusive prefix
    if (idx == n) offs[n] = E;
}

__global__ void fill_kernel(const int* __restrict__ src, const int* __restrict__ dst,
                            const float* __restrict__ dis, const int* __restrict__ offs,
                            const int* __restrict__ rank, int2* __restrict__ csr, int E) {
    int i = blockIdx.x * blockDim.x + threadIdx.x;
    int st = gridDim.x * blockDim.x;
    for (; i < E; i += st) {
        int d = dst[i];
        int s = src[i];
        int p = offs[d] + rank[i];
        csr[p] = make_int2(s, __float_as_int(dis[s]));
    }
}

// ---------------------------------------------------------------------------
// GEMM: Y[r][c] = sum_k X[r][k] * W[k][c];  K = 128 fixed; NOUT in {128, 64}.
// BM = 32 rows/block, 256 threads, W fully staged in LDS, X tile in LDS.
// ---------------------------------------------------------------------------
template <int NOUT>
__global__ __launch_bounds__(256) void gemm_kernel(const float* __restrict__ X,
                                                   const float* __restrict__ W,
                                                   float* __restrict__ Y, int nrows) {
    __shared__ float Ws[128 * NOUT];
    __shared__ float Xs[32 * 128];
    const int t = threadIdx.x;

    {
        const float4* W4 = (const float4*)W;
        float4* Ws4 = (float4*)Ws;
        constexpr int WV = 128 * NOUT / 4;
        for (int i = t; i < WV; i += 256) Ws4[i] = W4[i];
    }
    const int row0 = blockIdx.x * 32;
    {
        float4* Xs4 = (float4*)Xs;
        const float4* X4 = (const float4*)X;
        for (int i = t; i < 32 * 128 / 4; i += 256) {
            int r = i >> 5;
            int rr = row0 + r;
            float4 v = make_float4(0.f, 0.f, 0.f, 0.f);
            if (rr < nrows) v = X4[(size_t)rr * 32 + (i & 31)];
            Xs4[i] = v;
        }
    }
    __syncthreads();

    constexpr int CPT = NOUT / 32;
    const int tr = t >> 5;
    const int tcv = t & 31;

    float acc[4][CPT];
#pragma unroll
    for (int i = 0; i < 4; ++i)
#pragma unroll
        for (int j = 0; j < CPT; ++j) acc[i][j] = 0.f;

    const float4* Xs4 = (const float4*)Xs;

    for (int k = 0; k < 128; k += 4) {
        float4 a[4];
#pragma unroll
        for (int i = 0; i < 4; ++i) a[i] = Xs4[(size_t)(tr * 4 + i) * 32 + (k >> 2)];
#pragma unroll
        for (int kk = 0; kk < 4; ++kk) {
            if constexpr (CPT == 4) {
                float4 b = ((const float4*)Ws)[(size_t)(k + kk) * 32 + tcv];
#pragma unroll
                for (int i = 0; i < 4; ++i) {
                    float av = reinterpret_cast<const float*>(&a[i])[kk];
                    acc[i][0] = fmaf(av, b.x, acc[i][0]);
                    acc[i][1] = fmaf(av, b.y, acc[i][1]);
                    acc[i][2] = fmaf(av, b.z, acc[i][2]);
                    acc[i][3] = fmaf(av, b.w, acc[i][3]);
                }
            } else {
                float2 b = ((const float2*)Ws)[(size_t)(k + kk) * 32 + tcv];
#pragma unroll
                for (int i = 0; i < 4; ++i) {
                    float av = reinterpret_cast<const float*>(&a[i])[kk];
                    acc[i][0] = fmaf(av, b.x, acc[i][0]);
                    acc[i][1] = fmaf(av, b.y, acc[i][1]);
                }
            }
        }
    }

#pragma unroll
    for (int i = 0; i < 4; ++i) {
        int row = row0 + tr * 4 + i;
        if (row < nrows) {
            if constexpr (CPT == 4) {
                float4 v = make_float4(acc[i][0], acc[i][1], acc[i][2], acc[i][3]);
                ((float4*)Y)[(size_t)row * (NOUT / 4) + tcv] = v;
            } else {
                float2 v = make_float2(acc[i][0], acc[i][1]);
                ((float2*)Y)[(size_t)row * (NOUT / 2) + tcv] = v;
            }
        }
    }
}

// ---------------------------------------------------------------------------
// Aggregation: one block (128 thr = 2 waves) per node. Each WAVE reads whole
// rows (float2/lane for F=128, float/lane for F=64); waves split the edge
// range; LDS combine. Predicated unroll-4 keeps 4 row-gathers in flight.
// MUST be launched with 128 threads for both F=128 and F=64.
// ---------------------------------------------------------------------------
template <int F, bool RELU>
__global__ __launch_bounds__(128) void agg_kernel(const float* __restrict__ h,
                                                  const float* __restrict__ dis,
                                                  const int* __restrict__ offs,
                                                  const int2* __restrict__ csr,
                                                  const float* __restrict__ bias,
                                                  float* __restrict__ out) {
    constexpr int VPL = F / 64;   // floats per lane: 2 (F=128) or 1 (F=64)
    const int d = blockIdx.x;
    const int wave = threadIdx.x >> 6;
    const int lane = threadIdx.x & 63;
    const int beg = offs[d];
    const int end = offs[d + 1];
    const int len = end - beg;
    const int half = len >> 1;
    const int wbeg = beg + (wave ? half : 0);
    const int wend = wave ? end : beg + half;

    float ax[4], ay[4];
#pragma unroll
    for (int j = 0; j < 4; ++j) { ax[j] = 0.f; ay[j] = 0.f; }

    for (int i = wbeg; i < wend; i += 4) {
        int   s[4];
        float w[4];
#pragma unroll
        for (int j = 0; j < 4; ++j) {
            int idx = i + j;
            bool ok = idx < wend;
            idx = ok ? idx : wend - 1;       // clamp (loop entered => valid)
            int2 sw = csr[idx];
            s[j] = sw.x;
            w[j] = ok ? __int_as_float(sw.y) : 0.f;
        }
        if constexpr (VPL == 2) {
#pragma unroll
            for (int j = 0; j < 4; ++j) {
                float2 v = ((const float2*)(h + (size_t)s[j] * F))[lane];
                ax[j] = fmaf(w[j], v.x, ax[j]);
                ay[j] = fmaf(w[j], v.y, ay[j]);
            }
        } else {
#pragma unroll
            for (int j = 0; j < 4; ++j) {
                float v = h[(size_t)s[j] * F + lane];
                ax[j] = fmaf(w[j], v, ax[j]);
            }
        }
    }

    __shared__ float red[2][F];
    if constexpr (VPL == 2) {
        float2 sum = make_float2((ax[0] + ax[1]) + (ax[2] + ax[3]),
                                 (ay[0] + ay[1]) + (ay[2] + ay[3]));
        ((float2*)red[wave])[lane] = sum;
    } else {
        red[wave][lane] = (ax[0] + ax[1]) + (ax[2] + ax[3]);
    }
    __syncthreads();

    const int t = threadIdx.x;
    if (t < F) {
        float v = red[0][t] + red[1][t];
        float dd = dis[d];
        float r = fmaf(dd, v, dd * dd * h[(size_t)d * F + t]) + bias[t];
        if (RELU) r = fmaxf(r, 0.f);
        out[(size_t)d * F + t] = r;
    }
}

// ---------------------------------------------------------------------------

extern "C" void kernel_launch(void* const* d_in, const int* in_sizes, int n_in,
                              void* d_out, int out_size, void* d_ws, size_t ws_size,
                              hipStream_t stream) {
    const float* x  = (const float*)d_in[0];
    const int*   ei = (const int*)d_in[1];
    const float* W1 = (const float*)d_in[2];
    const float* b1 = (const float*)d_in[3];
    const float* W2 = (const float*)d_in[4];
    const float* b2 = (const float*)d_in[5];
    const float* W3 = (const float*)d_in[6];
    const float* b3 = (const float*)d_in[7];

    const int N = in_sizes[0] / 128;
    const int E = in_sizes[1] / 2;
    const int* src = ei;
    const int* dst = ei + E;
    float* out = (float*)d_out;

    char* w = (char*)d_ws;
    auto take = [&](size_t bytes) -> void* {
        void* p = (void*)w;
        w += (bytes + 255) & ~(size_t)255;
        return p;
    };
    int*   counts = (int*)take((size_t)N * 4);
    int*   offs   = (int*)take((size_t)(N + 1) * 4);
    float* dis    = (float*)take((size_t)N * 4);
    int*   bsum   = (int*)take((size_t)1024 * 4);
    int2*  csr    = (int2*)take((size_t)E * 8);
    float* G      = (float*)take((size_t)N * 128 * 4);
    float* H      = (float*)take((size_t)N * 128 * 4);
    // rank is only live between count_kernel and fill_kernel; G is only live
    // from the first GEMM onward (same stream => sequential). Alias them.
    int*   rank   = (int*)G;

    const int NBLK = (N + 256) / 256;

    // --- graph preprocessing ---
    zero_ints<<<256, 256, 0, stream>>>(counts, N);
    count_kernel<<<2048, 256, 0, stream>>>(dst, counts, rank, E);
    dis_kernel<<<(N + 255) / 256, 256, 0, stream>>>(counts, dis, N);
    block_sum_kernel<<<NBLK, 256, 0, stream>>>(counts, bsum, N);
    small_scan_kernel<<<1, 256, 0, stream>>>(bsum, NBLK);
    scan_block_kernel<<<NBLK, 256, 0, stream>>>(counts, bsum, offs, N, E);
    fill_kernel<<<2048, 256, 0, stream>>>(src, dst, dis, offs, rank, csr, E);

    const int gblocks = (N + 31) / 32;

    // layer 1
    gemm_kernel<128><<<gblocks, 256, 0, stream>>>(x, W1, G, N);
    agg_kernel<128, true><<<N, 128, 0, stream>>>(G, dis, offs, csr, b1, H);
    // layer 2
    gemm_kernel<128><<<gblocks, 256, 0, stream>>>(H, W2, G, N);
    agg_kernel<128, true><<<N, 128, 0, stream>>>(G, dis, offs, csr, b2, H);
    // layer 3 (project to 64 first, then aggregate on 64 dims)
    gemm_kernel<64><<<gblocks, 256, 0, stream>>>(H, W3, G, N);
    agg_kernel<64, false><<<N, 128, 0, stream>>>(G, dis, offs, csr, b3, out);
}

// Round 5
// 327.594 us; speedup vs baseline: 1.5703x; 1.0072x over previous
//
#include <hip/hip_runtime.h>
#include <math.h>

// ---------------------------------------------------------------------------
// GCN 3-layer: per layer  h = X @ W ;  out[d] = dis[d]*sum_{e:dst=d} dis[src]*h[src]
//                                             + dis[d]^2*h[d] + b ; relu (layers 1,2)
// CSR-by-dst built on device each call. csr entry = int2{src, bits(dis[src])}.
// ---------------------------------------------------------------------------

// counts in-degree AND records each edge's rank within its dst bucket
__global__ void count_kernel(const int* __restrict__ dst, int* __restrict__ counts,
                             int* __restrict__ rank, int E) {
    int i = blockIdx.x * blockDim.x + threadIdx.x;
    int st = gridDim.x * blockDim.x;
    for (; i < E; i += st) rank[i] = atomicAdd(&counts[dst[i]], 1);
}

// --------------------------- multi-block scan ------------------------------
__global__ __launch_bounds__(256) void block_sum_kernel(const int* __restrict__ counts,
                                                        int* __restrict__ bsum, int n) {
    const int b = blockIdx.x;
    const int t = threadIdx.x;
    const int idx = b * 256 + t;
    int v = (idx < n) ? counts[idx] : 0;
#pragma unroll
    for (int o = 32; o > 0; o >>= 1) v += __shfl_down(v, o, 64);
    __shared__ int ws[4];
    if ((t & 63) == 0) ws[t >> 6] = v;
    __syncthreads();
    if (t == 0) bsum[b] = ws[0] + ws[1] + ws[2] + ws[3];
}

__global__ __launch_bounds__(256) void small_scan_kernel(int* __restrict__ bsum, int nb) {
    __shared__ int sm[256];
    const int t = threadIdx.x;
    int v = (t < nb) ? bsum[t] : 0;
    sm[t] = v;
    __syncthreads();
    for (int o = 1; o < 256; o <<= 1) {
        int x = (t >= o) ? sm[t - o] : 0;
        __syncthreads();
        sm[t] += x;
        __syncthreads();
    }
    if (t < nb) bsum[t] = sm[t] - v;   // exclusive
}

// scan within block + write dis (fused: reads counts anyway)
__global__ __launch_bounds__(256) void scan_block_kernel(const int* __restrict__ counts,
                                                         const int* __restrict__ bsum,
                                                         int* __restrict__ offs,
                                                         float* __restrict__ dis,
                                                         int n, int E) {
    const int b = blockIdx.x;
    const int t = threadIdx.x;
    const int idx = b * 256 + t;
    int v = (idx < n) ? counts[idx] : 0;
    if (idx < n) dis[idx] = rsqrtf((float)(v + 1));   // +1 self-loop
    __shared__ int sm[256];
    sm[t] = v;
    __syncthreads();
    for (int o = 1; o < 256; o <<= 1) {
        int x = (t >= o) ? sm[t - o] : 0;
        __syncthreads();
        sm[t] += x;
        __syncthreads();
    }
    if (idx < n) offs[idx] = bsum[b] + sm[t] - v;   // exclusive prefix
    if (idx == n) offs[n] = E;
}

__global__ void fill_kernel(const int* __restrict__ src, const int* __restrict__ dst,
                            const float* __restrict__ dis, const int* __restrict__ offs,
                            const int* __restrict__ rank, int2* __restrict__ csr, int E) {
    int i = blockIdx.x * blockDim.x + threadIdx.x;
    int st = gridDim.x * blockDim.x;
    for (; i < E; i += st) {
        int d = dst[i];
        int s = src[i];
        int p = offs[d] + rank[i];
        csr[p] = make_int2(s, __float_as_int(dis[s]));
    }
}

// ---------------------------------------------------------------------------
// GEMM: Y[r][c] = sum_k X[r][k] * W[k][c];  K = 128 fixed; NOUT in {128, 64}.
// ---------------------------------------------------------------------------
template <int NOUT>
__global__ __launch_bounds__(256) void gemm_kernel(const float* __restrict__ X,
                                                   const float* __restrict__ W,
                                                   float* __restrict__ Y, int nrows) {
    __shared__ float Ws[128 * NOUT];
    __shared__ float Xs[32 * 128];
    const int t = threadIdx.x;

    {
        const float4* W4 = (const float4*)W;
        float4* Ws4 = (float4*)Ws;
        constexpr int WV = 128 * NOUT / 4;
        for (int i = t; i < WV; i += 256) Ws4[i] = W4[i];
    }
    const int row0 = blockIdx.x * 32;
    {
        float4* Xs4 = (float4*)Xs;
        const float4* X4 = (const float4*)X;
        for (int i = t; i < 32 * 128 / 4; i += 256) {
            int r = i >> 5;
            int rr = row0 + r;
            float4 v = make_float4(0.f, 0.f, 0.f, 0.f);
            if (rr < nrows) v = X4[(size_t)rr * 32 + (i & 31)];
            Xs4[i] = v;
        }
    }
    __syncthreads();

    constexpr int CPT = NOUT / 32;
    const int tr = t >> 5;
    const int tcv = t & 31;

    float acc[4][CPT];
#pragma unroll
    for (int i = 0; i < 4; ++i)
#pragma unroll
        for (int j = 0; j < CPT; ++j) acc[i][j] = 0.f;

    const float4* Xs4 = (const float4*)Xs;

    for (int k = 0; k < 128; k += 4) {
        float4 a[4];
#pragma unroll
        for (int i = 0; i < 4; ++i) a[i] = Xs4[(size_t)(tr * 4 + i) * 32 + (k >> 2)];
#pragma unroll
        for (int kk = 0; kk < 4; ++kk) {
            if constexpr (CPT == 4) {
                float4 b = ((const float4*)Ws)[(size_t)(k + kk) * 32 + tcv];
#pragma unroll
                for (int i = 0; i < 4; ++i) {
                    float av = reinterpret_cast<const float*>(&a[i])[kk];
                    acc[i][0] = fmaf(av, b.x, acc[i][0]);
                    acc[i][1] = fmaf(av, b.y, acc[i][1]);
                    acc[i][2] = fmaf(av, b.z, acc[i][2]);
                    acc[i][3] = fmaf(av, b.w, acc[i][3]);
                }
            } else {
                float2 b = ((const float2*)Ws)[(size_t)(k + kk) * 32 + tcv];
#pragma unroll
                for (int i = 0; i < 4; ++i) {
                    float av = reinterpret_cast<const float*>(&a[i])[kk];
                    acc[i][0] = fmaf(av, b.x, acc[i][0]);
                    acc[i][1] = fmaf(av, b.y, acc[i][1]);
                }
            }
        }
    }

#pragma unroll
    for (int i = 0; i < 4; ++i) {
        int row = row0 + tr * 4 + i;
        if (row < nrows) {
            if constexpr (CPT == 4) {
                float4 v = make_float4(acc[i][0], acc[i][1], acc[i][2], acc[i][3]);
                ((float4*)Y)[(size_t)row * (NOUT / 4) + tcv] = v;
            } else {
                float2 v = make_float2(acc[i][0], acc[i][1]);
                ((float2*)Y)[(size_t)row * (NOUT / 2) + tcv] = v;
            }
        }
    }
}

// ---------------------------------------------------------------------------
// Aggregation: one block (128 thr = 2 waves) per node. Each WAVE reads whole
// rows (float2/lane for F=128, float/lane for F=64); waves split the edge
// range; LDS combine. Unroll-4 over FULL groups only (no wasted loads);
// exact single-edge tail. MUST launch with 128 threads for both F.
// ---------------------------------------------------------------------------
template <int F, bool RELU>
__global__ __launch_bounds__(128) void agg_kernel(const float* __restrict__ h,
                                                  const float* __restrict__ dis,
                                                  const int* __restrict__ offs,
                                                  const int2* __restrict__ csr,
                                                  const float* __restrict__ bias,
                                                  float* __restrict__ out) {
    constexpr int VPL = F / 64;   // floats per lane: 2 (F=128) or 1 (F=64)
    const int d = blockIdx.x;
    const int wave = threadIdx.x >> 6;
    const int lane = threadIdx.x & 63;
    const int beg = offs[d];
    const int end = offs[d + 1];
    const int half = (end - beg) >> 1;
    const int wbeg = beg + (wave ? half : 0);
    const int wend = wave ? end : beg + half;

    float ax[4], ay[4];
#pragma unroll
    for (int j = 0; j < 4; ++j) { ax[j] = 0.f; ay[j] = 0.f; }

    int i = wbeg;
    for (; i + 4 <= wend; i += 4) {
        int2 sw[4];
#pragma unroll
        for (int j = 0; j < 4; ++j) sw[j] = csr[i + j];
        if constexpr (VPL == 2) {
            float2 v[4];
#pragma unroll
            for (int j = 0; j < 4; ++j)
                v[j] = ((const float2*)(h + (size_t)sw[j].x * F))[lane];
#pragma unroll
            for (int j = 0; j < 4; ++j) {
                float w = __int_as_float(sw[j].y);
                ax[j] = fmaf(w, v[j].x, ax[j]);
                ay[j] = fmaf(w, v[j].y, ay[j]);
            }
        } else {
            float v[4];
#pragma unroll
            for (int j = 0; j < 4; ++j) v[j] = h[(size_t)sw[j].x * F + lane];
#pragma unroll
            for (int j = 0; j < 4; ++j)
                ax[j] = fmaf(__int_as_float(sw[j].y), v[j], ax[j]);
        }
    }
    // exact tail (<=3 edges)
    for (; i < wend; ++i) {
        int2 sw = csr[i];
        float w = __int_as_float(sw.y);
        if constexpr (VPL == 2) {
            float2 v = ((const float2*)(h + (size_t)sw.x * F))[lane];
            ax[0] = fmaf(w, v.x, ax[0]);
            ay[0] = fmaf(w, v.y, ay[0]);
        } else {
            ax[0] = fmaf(w, h[(size_t)sw.x * F + lane], ax[0]);
        }
    }

    __shared__ float red[2][F];
    if constexpr (VPL == 2) {
        float2 sum = make_float2((ax[0] + ax[1]) + (ax[2] + ax[3]),
                                 (ay[0] + ay[1]) + (ay[2] + ay[3]));
        ((float2*)red[wave])[lane] = sum;
    } else {
        red[wave][lane] = (ax[0] + ax[1]) + (ax[2] + ax[3]);
    }
    __syncthreads();

    const int t = threadIdx.x;
    if (t < F) {
        float v = red[0][t] + red[1][t];
        float dd = dis[d];
        float r = fmaf(dd, v, dd * dd * h[(size_t)d * F + t]) + bias[t];
        if (RELU) r = fmaxf(r, 0.f);
        out[(size_t)d * F + t] = r;
    }
}

// ---------------------------------------------------------------------------

extern "C" void kernel_launch(void* const* d_in, const int* in_sizes, int n_in,
                              void* d_out, int out_size, void* d_ws, size_t ws_size,
                              hipStream_t stream) {
    const float* x  = (const float*)d_in[0];
    const int*   ei = (const int*)d_in[1];
    const float* W1 = (const float*)d_in[2];
    const float* b1 = (const float*)d_in[3];
    const float* W2 = (const float*)d_in[4];
    const float* b2 = (const float*)d_in[5];
    const float* W3 = (const float*)d_in[6];
    const float* b3 = (const float*)d_in[7];

    const int N = in_sizes[0] / 128;
    const int E = in_sizes[1] / 2;
    const int* src = ei;
    const int* dst = ei + E;
    float* out = (float*)d_out;

    char* w = (char*)d_ws;
    auto take = [&](size_t bytes) -> void* {
        void* p = (void*)w;
        w += (bytes + 255) & ~(size_t)255;
        return p;
    };
    int*   counts = (int*)take((size_t)N * 4);
    int*   offs   = (int*)take((size_t)(N + 1) * 4);
    float* dis    = (float*)take((size_t)N * 4);
    int*   bsum   = (int*)take((size_t)1024 * 4);
    int2*  csr    = (int2*)take((size_t)E * 8);
    float* G      = (float*)take((size_t)N * 128 * 4);
    float* H      = (float*)take((size_t)N * 128 * 4);
    // rank is only live between count_kernel and fill_kernel; G is only live
    // from the first GEMM onward (same stream => sequential). Alias them.
    int*   rank   = (int*)G;

    const int NBLK = (N + 256) / 256;

    // --- graph preprocessing ---
    hipMemsetAsync(counts, 0, (size_t)N * 4, stream);
    count_kernel<<<2048, 256, 0, stream>>>(dst, counts, rank, E);
    block_sum_kernel<<<NBLK, 256, 0, stream>>>(counts, bsum, N);
    small_scan_kernel<<<1, 256, 0, stream>>>(bsum, NBLK);
    scan_block_kernel<<<NBLK, 256, 0, stream>>>(counts, bsum, offs, dis, N, E);
    fill_kernel<<<2048, 256, 0, stream>>>(src, dst, dis, offs, rank, csr, E);

    const int gblocks = (N + 31) / 32;

    // layer 1
    gemm_kernel<128><<<gblocks, 256, 0, stream>>>(x, W1, G, N);
    agg_kernel<128, true><<<N, 128, 0, stream>>>(G, dis, offs, csr, b1, H);
    // layer 2
    gemm_kernel<128><<<gblocks, 256, 0, stream>>>(H, W2, G, N);
    agg_kernel<128, true><<<N, 128, 0, stream>>>(G, dis, offs, csr, b2, H);
    // layer 3 (project to 64 first, then aggregate on 64 dims)
    gemm_kernel<64><<<gblocks, 256, 0, stream>>>(H, W3, G, N);
    agg_kernel<64, false><<<N, 128, 0, stream>>>(G, dis, offs, csr, b3, out);
}

// Round 6
// 294.395 us; speedup vs baseline: 1.7473x; 1.1128x over previous
//
#include <hip/hip_runtime.h>
#include <hip/hip_fp16.h>
#include <math.h>

// ---------------------------------------------------------------------------
// GCN 3-layer. Per layer: P = X@W (fp32 GEMM, epilogue stores P as fp16);
// agg: out[d] = dis_d * sum_{e:dst=d} dis_src * P[src] + dis_d^2 * P[d] + b
// (fp32 accumulate, fp16 gather rows -> halves L2-miss traffic, the measured
// bottleneck: ~3.2 TB/s on the random-row L2-miss path, invariant across
// R2/R4/R5 structures). CSR-by-dst built on device each call.
// ---------------------------------------------------------------------------

// counts in-degree AND records each edge's rank within its dst bucket
__global__ void count_kernel(const int* __restrict__ dst, int* __restrict__ counts,
                             int* __restrict__ rank, int E) {
    int i = blockIdx.x * blockDim.x + threadIdx.x;
    int st = gridDim.x * blockDim.x;
    for (; i < E; i += st) rank[i] = atomicAdd(&counts[dst[i]], 1);
}

// --------------------------- multi-block scan ------------------------------
__global__ __launch_bounds__(256) void block_sum_kernel(const int* __restrict__ counts,
                                                        int* __restrict__ bsum, int n) {
    const int b = blockIdx.x;
    const int t = threadIdx.x;
    const int idx = b * 256 + t;
    int v = (idx < n) ? counts[idx] : 0;
#pragma unroll
    for (int o = 32; o > 0; o >>= 1) v += __shfl_down(v, o, 64);
    __shared__ int ws[4];
    if ((t & 63) == 0) ws[t >> 6] = v;
    __syncthreads();
    if (t == 0) bsum[b] = ws[0] + ws[1] + ws[2] + ws[3];
}

__global__ __launch_bounds__(256) void small_scan_kernel(int* __restrict__ bsum, int nb) {
    __shared__ int sm[256];
    const int t = threadIdx.x;
    int v = (t < nb) ? bsum[t] : 0;
    sm[t] = v;
    __syncthreads();
    for (int o = 1; o < 256; o <<= 1) {
        int x = (t >= o) ? sm[t - o] : 0;
        __syncthreads();
        sm[t] += x;
        __syncthreads();
    }
    if (t < nb) bsum[t] = sm[t] - v;   // exclusive
}

// scan within block + write dis (fused: reads counts anyway)
__global__ __launch_bounds__(256) void scan_block_kernel(const int* __restrict__ counts,
                                                         const int* __restrict__ bsum,
                                                         int* __restrict__ offs,
                                                         float* __restrict__ dis,
                                                         int n, int E) {
    const int b = blockIdx.x;
    const int t = threadIdx.x;
    const int idx = b * 256 + t;
    int v = (idx < n) ? counts[idx] : 0;
    if (idx < n) dis[idx] = rsqrtf((float)(v + 1));   // +1 self-loop
    __shared__ int sm[256];
    sm[t] = v;
    __syncthreads();
    for (int o = 1; o < 256; o <<= 1) {
        int x = (t >= o) ? sm[t - o] : 0;
        __syncthreads();
        sm[t] += x;
        __syncthreads();
    }
    if (idx < n) offs[idx] = bsum[b] + sm[t] - v;   // exclusive prefix
    if (idx == n) offs[n] = E;
}

__global__ void fill_kernel(const int* __restrict__ src, const int* __restrict__ dst,
                            const float* __restrict__ dis, const int* __restrict__ offs,
                            const int* __restrict__ rank, int2* __restrict__ csr, int E) {
    int i = blockIdx.x * blockDim.x + threadIdx.x;
    int st = gridDim.x * blockDim.x;
    for (; i < E; i += st) {
        int d = dst[i];
        int s = src[i];
        int p = offs[d] + rank[i];
        csr[p] = make_int2(s, __float_as_int(dis[s]));
    }
}

// ---------------------------------------------------------------------------
// GEMM: P[r][c] = sum_k X[r][k] * W[k][c];  K = 128; NOUT in {128, 64}.
// fp32 input/compute, fp16 output (gather source for agg).
// ---------------------------------------------------------------------------
template <int NOUT>
__global__ __launch_bounds__(256) void gemm_kernel(const float* __restrict__ X,
                                                   const float* __restrict__ W,
                                                   __half* __restrict__ Y, int nrows) {
    __shared__ float Ws[128 * NOUT];
    __shared__ float Xs[32 * 128];
    const int t = threadIdx.x;

    {
        const float4* W4 = (const float4*)W;
        float4* Ws4 = (float4*)Ws;
        constexpr int WV = 128 * NOUT / 4;
        for (int i = t; i < WV; i += 256) Ws4[i] = W4[i];
    }
    const int row0 = blockIdx.x * 32;
    {
        float4* Xs4 = (float4*)Xs;
        const float4* X4 = (const float4*)X;
        for (int i = t; i < 32 * 128 / 4; i += 256) {
            int r = i >> 5;
            int rr = row0 + r;
            float4 v = make_float4(0.f, 0.f, 0.f, 0.f);
            if (rr < nrows) v = X4[(size_t)rr * 32 + (i & 31)];
            Xs4[i] = v;
        }
    }
    __syncthreads();

    constexpr int CPT = NOUT / 32;
    const int tr = t >> 5;
    const int tcv = t & 31;

    float acc[4][CPT];
#pragma unroll
    for (int i = 0; i < 4; ++i)
#pragma unroll
        for (int j = 0; j < CPT; ++j) acc[i][j] = 0.f;

    const float4* Xs4 = (const float4*)Xs;

    for (int k = 0; k < 128; k += 4) {
        float4 a[4];
#pragma unroll
        for (int i = 0; i < 4; ++i) a[i] = Xs4[(size_t)(tr * 4 + i) * 32 + (k >> 2)];
#pragma unroll
        for (int kk = 0; kk < 4; ++kk) {
            if constexpr (CPT == 4) {
                float4 b = ((const float4*)Ws)[(size_t)(k + kk) * 32 + tcv];
#pragma unroll
                for (int i = 0; i < 4; ++i) {
                    float av = reinterpret_cast<const float*>(&a[i])[kk];
                    acc[i][0] = fmaf(av, b.x, acc[i][0]);
                    acc[i][1] = fmaf(av, b.y, acc[i][1]);
                    acc[i][2] = fmaf(av, b.z, acc[i][2]);
                    acc[i][3] = fmaf(av, b.w, acc[i][3]);
                }
            } else {
                float2 b = ((const float2*)Ws)[(size_t)(k + kk) * 32 + tcv];
#pragma unroll
                for (int i = 0; i < 4; ++i) {
                    float av = reinterpret_cast<const float*>(&a[i])[kk];
                    acc[i][0] = fmaf(av, b.x, acc[i][0]);
                    acc[i][1] = fmaf(av, b.y, acc[i][1]);
                }
            }
        }
    }

#pragma unroll
    for (int i = 0; i < 4; ++i) {
        int row = row0 + tr * 4 + i;
        if (row < nrows) {
            if constexpr (CPT == 4) {
                __half2 p0 = __floats2half2_rn(acc[i][0], acc[i][1]);  // cols 4tcv, +1
                __half2 p1 = __floats2half2_rn(acc[i][2], acc[i][3]);  // cols +2, +3
                uint2 u;
                u.x = *reinterpret_cast<unsigned*>(&p0);
                u.y = *reinterpret_cast<unsigned*>(&p1);
                ((uint2*)Y)[(size_t)row * 32 + tcv] = u;   // 128 fp16 = 32 uint2/row
            } else {
                __half2 p0 = __floats2half2_rn(acc[i][0], acc[i][1]);  // cols 2tcv, +1
                ((unsigned*)Y)[(size_t)row * 32 + tcv] =
                    *reinterpret_cast<unsigned*>(&p0);      // 64 fp16 = 32 uint/row
            }
        }
    }
}

// ---------------------------------------------------------------------------
// Aggregation: one block (128 thr = 2 waves) per node; waves split edge range;
// LDS combine. fp16 gather rows: F=128 -> uint (2 fp16)/lane = 256B/row;
// F=64 -> __half/lane = 128B/row. fp32 accumulate. Launch with 128 threads.
// ---------------------------------------------------------------------------
template <int F, bool RELU>
__global__ __launch_bounds__(128) void agg_kernel(const __half* __restrict__ h,
                                                  const float* __restrict__ dis,
                                                  const int* __restrict__ offs,
                                                  const int2* __restrict__ csr,
                                                  const float* __restrict__ bias,
                                                  float* __restrict__ out) {
    const int d = blockIdx.x;
    const int wave = threadIdx.x >> 6;
    const int lane = threadIdx.x & 63;
    const int beg = offs[d];
    const int end = offs[d + 1];
    const int half = (end - beg) >> 1;
    const int wbeg = beg + (wave ? half : 0);
    const int wend = wave ? end : beg + half;

    float ax[4], ay[4];
#pragma unroll
    for (int j = 0; j < 4; ++j) { ax[j] = 0.f; ay[j] = 0.f; }

    int i = wbeg;
    for (; i + 4 <= wend; i += 4) {
        int2 sw[4];
#pragma unroll
        for (int j = 0; j < 4; ++j) sw[j] = csr[i + j];
        if constexpr (F == 128) {
            unsigned v[4];
#pragma unroll
            for (int j = 0; j < 4; ++j)
                v[j] = ((const unsigned*)(h + (size_t)sw[j].x * F))[lane];
#pragma unroll
            for (int j = 0; j < 4; ++j) {
                float w = __int_as_float(sw[j].y);
                float2 vf = __half22float2(*reinterpret_cast<__half2*>(&v[j]));
                ax[j] = fmaf(w, vf.x, ax[j]);
                ay[j] = fmaf(w, vf.y, ay[j]);
            }
        } else {
            __half v[4];
#pragma unroll
            for (int j = 0; j < 4; ++j) v[j] = h[(size_t)sw[j].x * F + lane];
#pragma unroll
            for (int j = 0; j < 4; ++j)
                ax[j] = fmaf(__int_as_float(sw[j].y), __half2float(v[j]), ax[j]);
        }
    }
    // exact tail (<=3 edges)
    for (; i < wend; ++i) {
        int2 sw = csr[i];
        float w = __int_as_float(sw.y);
        if constexpr (F == 128) {
            unsigned v = ((const unsigned*)(h + (size_t)sw.x * F))[lane];
            float2 vf = __half22float2(*reinterpret_cast<__half2*>(&v));
            ax[0] = fmaf(w, vf.x, ax[0]);
            ay[0] = fmaf(w, vf.y, ay[0]);
        } else {
            ax[0] = fmaf(w, __half2float(h[(size_t)sw.x * F + lane]), ax[0]);
        }
    }

    __shared__ float red[2][F];
    if constexpr (F == 128) {
        float2 sum = make_float2((ax[0] + ax[1]) + (ax[2] + ax[3]),
                                 (ay[0] + ay[1]) + (ay[2] + ay[3]));
        ((float2*)red[wave])[lane] = sum;   // features 2*lane, 2*lane+1
    } else {
        red[wave][lane] = (ax[0] + ax[1]) + (ax[2] + ax[3]);
    }
    __syncthreads();

    const int t = threadIdx.x;
    if (t < F) {
        float v = red[0][t] + red[1][t];
        float dd = dis[d];
        float self = __half2float(h[(size_t)d * F + t]);
        float r = fmaf(dd, v, dd * dd * self) + bias[t];
        if (RELU) r = fmaxf(r, 0.f);
        out[(size_t)d * F + t] = r;
    }
}

// ---------------------------------------------------------------------------

extern "C" void kernel_launch(void* const* d_in, const int* in_sizes, int n_in,
                              void* d_out, int out_size, void* d_ws, size_t ws_size,
                              hipStream_t stream) {
    const float* x  = (const float*)d_in[0];
    const int*   ei = (const int*)d_in[1];
    const float* W1 = (const float*)d_in[2];
    const float* b1 = (const float*)d_in[3];
    const float* W2 = (const float*)d_in[4];
    const float* b2 = (const float*)d_in[5];
    const float* W3 = (const float*)d_in[6];
    const float* b3 = (const float*)d_in[7];

    const int N = in_sizes[0] / 128;
    const int E = in_sizes[1] / 2;
    const int* src = ei;
    const int* dst = ei + E;
    float* out = (float*)d_out;

    char* w = (char*)d_ws;
    auto take = [&](size_t bytes) -> void* {
        void* p = (void*)w;
        w += (bytes + 255) & ~(size_t)255;
        return p;
    };
    int*    counts = (int*)take((size_t)N * 4);
    int*    offs   = (int*)take((size_t)(N + 1) * 4);
    float*  dis    = (float*)take((size_t)N * 4);
    int*    bsum   = (int*)take((size_t)1024 * 4);
    int2*   csr    = (int2*)take((size_t)E * 8);
    __half* G16    = (__half*)take((size_t)N * 128 * 2);   // fp16 gather source
    float*  H      = (float*)take((size_t)N * 128 * 4);    // fp32 inter-layer
    // rank is only live between count_kernel and fill_kernel; G16 is only
    // written from the first GEMM onward (same stream => sequential). Alias.
    int*    rank   = (int*)G16;

    const int NBLK = (N + 256) / 256;

    // --- graph preprocessing ---
    hipMemsetAsync(counts, 0, (size_t)N * 4, stream);
    count_kernel<<<2048, 256, 0, stream>>>(dst, counts, rank, E);
    block_sum_kernel<<<NBLK, 256, 0, stream>>>(counts, bsum, N);
    small_scan_kernel<<<1, 256, 0, stream>>>(bsum, NBLK);
    scan_block_kernel<<<NBLK, 256, 0, stream>>>(counts, bsum, offs, dis, N, E);
    fill_kernel<<<2048, 256, 0, stream>>>(src, dst, dis, offs, rank, csr, E);

    const int gblocks = (N + 31) / 32;

    // layer 1
    gemm_kernel<128><<<gblocks, 256, 0, stream>>>(x, W1, G16, N);
    agg_kernel<128, true><<<N, 128, 0, stream>>>(G16, dis, offs, csr, b1, H);
    // layer 2
    gemm_kernel<128><<<gblocks, 256, 0, stream>>>(H, W2, G16, N);
    agg_kernel<128, true><<<N, 128, 0, stream>>>(G16, dis, offs, csr, b2, H);
    // layer 3 (project to 64 first, then aggregate on 64 dims)
    gemm_kernel<64><<<gblocks, 256, 0, stream>>>(H, W3, G16, N);
    agg_kernel<64, false><<<N, 128, 0, stream>>>(G16, dis, offs, csr, b3, out);
}

// Round 7
// 258.682 us; speedup vs baseline: 1.9886x; 1.1381x over previous
//
#include <hip/hip_runtime.h>
#include <hip/hip_fp16.h>
#include <math.h>

// ---------------------------------------------------------------------------
// GCN 3-layer. Per layer: P = X@W (fp32 GEMM), epilogue stores P' = dis_r*P_r
// as fp16. agg: out[d] = dis_d * (sum_{e:dst=d} P'[src] + P'[d]) + b ; relu.
// CSR payload is just the src index (weights folded into P' pre-scaling).
// One wave per node in agg, 8-deep gather pipeline, fp32 accumulate.
// ---------------------------------------------------------------------------

// counts in-degree AND records each edge's rank within its dst bucket
__global__ void count_kernel(const int* __restrict__ dst, int* __restrict__ counts,
                             int* __restrict__ rank, int E) {
    int i = blockIdx.x * blockDim.x + threadIdx.x;
    int st = gridDim.x * blockDim.x;
    for (; i < E; i += st) rank[i] = atomicAdd(&counts[dst[i]], 1);
}

// --------------------------- multi-block scan ------------------------------
__global__ __launch_bounds__(256) void block_sum_kernel(const int* __restrict__ counts,
                                                        int* __restrict__ bsum, int n) {
    const int b = blockIdx.x;
    const int t = threadIdx.x;
    const int idx = b * 256 + t;
    int v = (idx < n) ? counts[idx] : 0;
#pragma unroll
    for (int o = 32; o > 0; o >>= 1) v += __shfl_down(v, o, 64);
    __shared__ int ws[4];
    if ((t & 63) == 0) ws[t >> 6] = v;
    __syncthreads();
    if (t == 0) bsum[b] = ws[0] + ws[1] + ws[2] + ws[3];
}

__global__ __launch_bounds__(256) void small_scan_kernel(int* __restrict__ bsum, int nb) {
    __shared__ int sm[256];
    const int t = threadIdx.x;
    int v = (t < nb) ? bsum[t] : 0;
    sm[t] = v;
    __syncthreads();
    for (int o = 1; o < 256; o <<= 1) {
        int x = (t >= o) ? sm[t - o] : 0;
        __syncthreads();
        sm[t] += x;
        __syncthreads();
    }
    if (t < nb) bsum[t] = sm[t] - v;   // exclusive
}

// scan within block + write dis (fused: reads counts anyway)
__global__ __launch_bounds__(256) void scan_block_kernel(const int* __restrict__ counts,
                                                         const int* __restrict__ bsum,
                                                         int* __restrict__ offs,
                                                         float* __restrict__ dis,
                                                         int n, int E) {
    const int b = blockIdx.x;
    const int t = threadIdx.x;
    const int idx = b * 256 + t;
    int v = (idx < n) ? counts[idx] : 0;
    if (idx < n) dis[idx] = rsqrtf((float)(v + 1));   // +1 self-loop
    __shared__ int sm[256];
    sm[t] = v;
    __syncthreads();
    for (int o = 1; o < 256; o <<= 1) {
        int x = (t >= o) ? sm[t - o] : 0;
        __syncthreads();
        sm[t] += x;
        __syncthreads();
    }
    if (idx < n) offs[idx] = bsum[b] + sm[t] - v;   // exclusive prefix
    if (idx == n) offs[n] = E;
}

// csr entry = src index only (dis folded into pre-scaled rows)
__global__ void fill_kernel(const int* __restrict__ src, const int* __restrict__ dst,
                            const int* __restrict__ offs, const int* __restrict__ rank,
                            int* __restrict__ csr_s, int E) {
    int i = blockIdx.x * blockDim.x + threadIdx.x;
    int st = gridDim.x * blockDim.x;
    for (; i < E; i += st) {
        int p = offs[dst[i]] + rank[i];
        csr_s[p] = src[i];
    }
}

// ---------------------------------------------------------------------------
// GEMM: P[r][c] = sum_k X[r][k] * W[k][c];  K = 128; NOUT in {128, 64}.
// fp32 input/compute; epilogue scales row by dis[r], stores fp16.
// ---------------------------------------------------------------------------
template <int NOUT>
__global__ __launch_bounds__(256) void gemm_kernel(const float* __restrict__ X,
                                                   const float* __restrict__ W,
                                                   const float* __restrict__ dis,
                                                   __half* __restrict__ Y, int nrows) {
    __shared__ float Ws[128 * NOUT];
    __shared__ float Xs[32 * 128];
    const int t = threadIdx.x;

    {
        const float4* W4 = (const float4*)W;
        float4* Ws4 = (float4*)Ws;
        constexpr int WV = 128 * NOUT / 4;
        for (int i = t; i < WV; i += 256) Ws4[i] = W4[i];
    }
    const int row0 = blockIdx.x * 32;
    {
        float4* Xs4 = (float4*)Xs;
        const float4* X4 = (const float4*)X;
        for (int i = t; i < 32 * 128 / 4; i += 256) {
            int r = i >> 5;
            int rr = row0 + r;
            float4 v = make_float4(0.f, 0.f, 0.f, 0.f);
            if (rr < nrows) v = X4[(size_t)rr * 32 + (i & 31)];
            Xs4[i] = v;
        }
    }
    __syncthreads();

    constexpr int CPT = NOUT / 32;
    const int tr = t >> 5;
    const int tcv = t & 31;

    float acc[4][CPT];
#pragma unroll
    for (int i = 0; i < 4; ++i)
#pragma unroll
        for (int j = 0; j < CPT; ++j) acc[i][j] = 0.f;

    const float4* Xs4 = (const float4*)Xs;

    for (int k = 0; k < 128; k += 4) {
        float4 a[4];
#pragma unroll
        for (int i = 0; i < 4; ++i) a[i] = Xs4[(size_t)(tr * 4 + i) * 32 + (k >> 2)];
#pragma unroll
        for (int kk = 0; kk < 4; ++kk) {
            if constexpr (CPT == 4) {
                float4 b = ((const float4*)Ws)[(size_t)(k + kk) * 32 + tcv];
#pragma unroll
                for (int i = 0; i < 4; ++i) {
                    float av = reinterpret_cast<const float*>(&a[i])[kk];
                    acc[i][0] = fmaf(av, b.x, acc[i][0]);
                    acc[i][1] = fmaf(av, b.y, acc[i][1]);
                    acc[i][2] = fmaf(av, b.z, acc[i][2]);
                    acc[i][3] = fmaf(av, b.w, acc[i][3]);
                }
            } else {
                float2 b = ((const float2*)Ws)[(size_t)(k + kk) * 32 + tcv];
#pragma unroll
                for (int i = 0; i < 4; ++i) {
                    float av = reinterpret_cast<const float*>(&a[i])[kk];
                    acc[i][0] = fmaf(av, b.x, acc[i][0]);
                    acc[i][1] = fmaf(av, b.y, acc[i][1]);
                }
            }
        }
    }

#pragma unroll
    for (int i = 0; i < 4; ++i) {
        int row = row0 + tr * 4 + i;
        if (row < nrows) {
            float dd = dis[row];
            if constexpr (CPT == 4) {
                __half2 p0 = __floats2half2_rn(dd * acc[i][0], dd * acc[i][1]);
                __half2 p1 = __floats2half2_rn(dd * acc[i][2], dd * acc[i][3]);
                uint2 u;
                u.x = *reinterpret_cast<unsigned*>(&p0);
                u.y = *reinterpret_cast<unsigned*>(&p1);
                ((uint2*)Y)[(size_t)row * 32 + tcv] = u;   // 128 fp16 = 32 uint2/row
            } else {
                __half2 p0 = __floats2half2_rn(dd * acc[i][0], dd * acc[i][1]);
                ((unsigned*)Y)[(size_t)row * 32 + tcv] =
                    *reinterpret_cast<unsigned*>(&p0);      // 64 fp16 = 32 uint/row
            }
        }
    }
}

// ---------------------------------------------------------------------------
// Aggregation: ONE WAVE per node, 4 nodes per 256-thread block. No LDS, no
// syncthreads. 8-deep unrolled gather pipeline; fp32 accumulate.
// out[d] = dis[d]*(sum_in h'[s] + h'[d]) + bias ; optional relu.
// F=128: lane holds 2 feats (uint = half2). F=64: lane holds 1 feat (ushort).
// ---------------------------------------------------------------------------
template <int F, bool RELU>
__global__ __launch_bounds__(256) void agg_kernel(const __half* __restrict__ h,
                                                  const float* __restrict__ dis,
                                                  const int* __restrict__ offs,
                                                  const int* __restrict__ csr_s,
                                                  const float* __restrict__ bias,
                                                  float* __restrict__ out, int n) {
    const int d = blockIdx.x * 4 + (threadIdx.x >> 6);
    if (d >= n) return;
    const int lane = threadIdx.x & 63;
    const int beg = offs[d];
    const int end = offs[d + 1];

    float sx = 0.f, sy = 0.f;
    int i = beg;
    if constexpr (F == 128) {
        const unsigned* h32 = (const unsigned*)h;
        for (; i + 8 <= end; i += 8) {
            int s[8];
#pragma unroll
            for (int j = 0; j < 8; ++j) s[j] = csr_s[i + j];
            unsigned v[8];
#pragma unroll
            for (int j = 0; j < 8; ++j) v[j] = h32[(size_t)s[j] * 64 + lane];
#pragma unroll
            for (int j = 0; j < 8; ++j) {
                float2 vf = __half22float2(*reinterpret_cast<__half2*>(&v[j]));
                sx += vf.x;
                sy += vf.y;
            }
        }
        if (i + 4 <= end) {
            int s[4];
#pragma unroll
            for (int j = 0; j < 4; ++j) s[j] = csr_s[i + j];
            unsigned v[4];
#pragma unroll
            for (int j = 0; j < 4; ++j) v[j] = h32[(size_t)s[j] * 64 + lane];
#pragma unroll
            for (int j = 0; j < 4; ++j) {
                float2 vf = __half22float2(*reinterpret_cast<__half2*>(&v[j]));
                sx += vf.x;
                sy += vf.y;
            }
            i += 4;
        }
        for (; i < end; ++i) {
            unsigned v = h32[(size_t)csr_s[i] * 64 + lane];
            float2 vf = __half22float2(*reinterpret_cast<__half2*>(&v));
            sx += vf.x;
            sy += vf.y;
        }
        // self row
        {
            unsigned v = h32[(size_t)d * 64 + lane];
            float2 vf = __half22float2(*reinterpret_cast<__half2*>(&v));
            sx += vf.x;
            sy += vf.y;
        }
        float dd = dis[d];
        float2 b2 = ((const float2*)bias)[lane];
        float rx = fmaf(dd, sx, b2.x);
        float ry = fmaf(dd, sy, b2.y);
        if (RELU) {
            rx = fmaxf(rx, 0.f);
            ry = fmaxf(ry, 0.f);
        }
        ((float2*)(out + (size_t)d * F))[lane] = make_float2(rx, ry);
    } else {
        const unsigned short* h16 = (const unsigned short*)h;
        for (; i + 8 <= end; i += 8) {
            int s[8];
#pragma unroll
            for (int j = 0; j < 8; ++j) s[j] = csr_s[i + j];
            unsigned short v[8];
#pragma unroll
            for (int j = 0; j < 8; ++j) v[j] = h16[(size_t)s[j] * 64 + lane];
#pragma unroll
            for (int j = 0; j < 8; ++j)
                sx += __half2float(*reinterpret_cast<__half*>(&v[j]));
        }
        if (i + 4 <= end) {
            int s[4];
#pragma unroll
            for (int j = 0; j < 4; ++j) s[j] = csr_s[i + j];
            unsigned short v[4];
#pragma unroll
            for (int j = 0; j < 4; ++j) v[j] = h16[(size_t)s[j] * 64 + lane];
#pragma unroll
            for (int j = 0; j < 4; ++j)
                sx += __half2float(*reinterpret_cast<__half*>(&v[j]));
            i += 4;
        }
        for (; i < end; ++i) {
            unsigned short v = h16[(size_t)csr_s[i] * 64 + lane];
            sx += __half2float(*reinterpret_cast<__half*>(&v));
        }
        {
            unsigned short v = h16[(size_t)d * 64 + lane];
            sx += __half2float(*reinterpret_cast<__half*>(&v));
        }
        float dd = dis[d];
        float r = fmaf(dd, sx, bias[lane]);
        if (RELU) r = fmaxf(r, 0.f);
        out[(size_t)d * F + lane] = r;
    }
}

// ---------------------------------------------------------------------------

extern "C" void kernel_launch(void* const* d_in, const int* in_sizes, int n_in,
                              void* d_out, int out_size, void* d_ws, size_t ws_size,
                              hipStream_t stream) {
    const float* x  = (const float*)d_in[0];
    const int*   ei = (const int*)d_in[1];
    const float* W1 = (const float*)d_in[2];
    const float* b1 = (const float*)d_in[3];
    const float* W2 = (const float*)d_in[4];
    const float* b2 = (const float*)d_in[5];
    const float* W3 = (const float*)d_in[6];
    const float* b3 = (const float*)d_in[7];

    const int N = in_sizes[0] / 128;
    const int E = in_sizes[1] / 2;
    const int* src = ei;
    const int* dst = ei + E;
    float* out = (float*)d_out;

    char* w = (char*)d_ws;
    auto take = [&](size_t bytes) -> void* {
        void* p = (void*)w;
        w += (bytes + 255) & ~(size_t)255;
        return p;
    };
    int*    counts = (int*)take((size_t)N * 4);
    int*    offs   = (int*)take((size_t)(N + 1) * 4);
    float*  dis    = (float*)take((size_t)N * 4);
    int*    bsum   = (int*)take((size_t)1024 * 4);
    int*    csr_s  = (int*)take((size_t)E * 4);
    __half* G16    = (__half*)take((size_t)N * 128 * 2);   // fp16 pre-scaled rows
    float*  H      = (float*)take((size_t)N * 128 * 4);    // fp32 inter-layer
    // rank is only live between count_kernel and fill_kernel; G16 is only
    // written from the first GEMM onward (same stream => sequential). Alias.
    int*    rank   = (int*)G16;

    const int NBLK = (N + 256) / 256;

    // --- graph preprocessing ---
    hipMemsetAsync(counts, 0, (size_t)N * 4, stream);
    count_kernel<<<2048, 256, 0, stream>>>(dst, counts, rank, E);
    block_sum_kernel<<<NBLK, 256, 0, stream>>>(counts, bsum, N);
    small_scan_kernel<<<1, 256, 0, stream>>>(bsum, NBLK);
    scan_block_kernel<<<NBLK, 256, 0, stream>>>(counts, bsum, offs, dis, N, E);
    fill_kernel<<<2048, 256, 0, stream>>>(src, dst, offs, rank, csr_s, E);

    const int gblocks = (N + 31) / 32;
    const int ablocks = (N + 3) / 4;

    // layer 1
    gemm_kernel<128><<<gblocks, 256, 0, stream>>>(x, W1, dis, G16, N);
    agg_kernel<128, true><<<ablocks, 256, 0, stream>>>(G16, dis, offs, csr_s, b1, H, N);
    // layer 2
    gemm_kernel<128><<<gblocks, 256, 0, stream>>>(H, W2, dis, G16, N);
    agg_kernel<128, true><<<ablocks, 256, 0, stream>>>(G16, dis, offs, csr_s, b2, H, N);
    // layer 3 (project to 64 first, then aggregate on 64 dims)
    gemm_kernel<64><<<gblocks, 256, 0, stream>>>(H, W3, dis, G16, N);
    agg_kernel<64, false><<<ablocks, 256, 0, stream>>>(G16, dis, offs, csr_s, b3, out, N);
}

// Round 8
// 235.451 us; speedup vs baseline: 2.1848x; 1.0987x over previous
//
#include <hip/hip_runtime.h>
#include <hip/hip_fp16.h>
#include <math.h>

// ---------------------------------------------------------------------------
// GCN 3-layer. Per layer: P = X@W via split-fp16 MFMA (Xhi*Whi + Xhi*Wlo +
// Xlo*Whi, fp32 accum => fp32-grade accuracy), epilogue stores P' = dis_r*P_r
// as fp16 (gather source). agg: out[d] = dis_d*(sum_{dst=d} P'[src] + P'[d]) + b.
// agg outputs hi/lo fp16 H for the next layer's GEMM (fp32 for final layer).
// ---------------------------------------------------------------------------

typedef _Float16 half8 __attribute__((ext_vector_type(8)));
typedef float f32x4 __attribute__((ext_vector_type(4)));

// counts in-degree AND records each edge's rank within its dst bucket
__global__ void count_kernel(const int* __restrict__ dst, int* __restrict__ counts,
                             int* __restrict__ rank, int E) {
    int i = blockIdx.x * blockDim.x + threadIdx.x;
    int st = gridDim.x * blockDim.x;
    for (; i < E; i += st) rank[i] = atomicAdd(&counts[dst[i]], 1);
}

// --------------------------- multi-block scan ------------------------------
__global__ __launch_bounds__(256) void block_sum_kernel(const int* __restrict__ counts,
                                                        int* __restrict__ bsum, int n) {
    const int b = blockIdx.x;
    const int t = threadIdx.x;
    const int idx = b * 256 + t;
    int v = (idx < n) ? counts[idx] : 0;
#pragma unroll
    for (int o = 32; o > 0; o >>= 1) v += __shfl_down(v, o, 64);
    __shared__ int ws[4];
    if ((t & 63) == 0) ws[t >> 6] = v;
    __syncthreads();
    if (t == 0) bsum[b] = ws[0] + ws[1] + ws[2] + ws[3];
}

__global__ __launch_bounds__(256) void small_scan_kernel(int* __restrict__ bsum, int nb) {
    __shared__ int sm[256];
    const int t = threadIdx.x;
    int v = (t < nb) ? bsum[t] : 0;
    sm[t] = v;
    __syncthreads();
    for (int o = 1; o < 256; o <<= 1) {
        int x = (t >= o) ? sm[t - o] : 0;
        __syncthreads();
        sm[t] += x;
        __syncthreads();
    }
    if (t < nb) bsum[t] = sm[t] - v;   // exclusive
}

// scan within block + write dis (fused: reads counts anyway)
__global__ __launch_bounds__(256) void scan_block_kernel(const int* __restrict__ counts,
                                                         const int* __restrict__ bsum,
                                                         int* __restrict__ offs,
                                                         float* __restrict__ dis,
                                                         int n, int E) {
    const int b = blockIdx.x;
    const int t = threadIdx.x;
    const int idx = b * 256 + t;
    int v = (idx < n) ? counts[idx] : 0;
    if (idx < n) dis[idx] = rsqrtf((float)(v + 1));   // +1 self-loop
    __shared__ int sm[256];
    sm[t] = v;
    __syncthreads();
    for (int o = 1; o < 256; o <<= 1) {
        int x = (t >= o) ? sm[t - o] : 0;
        __syncthreads();
        sm[t] += x;
        __syncthreads();
    }
    if (idx < n) offs[idx] = bsum[b] + sm[t] - v;   // exclusive prefix
    if (idx == n) offs[n] = E;
}

// csr entry = src index only (dis folded into pre-scaled rows)
__global__ void fill_kernel(const int* __restrict__ src, const int* __restrict__ dst,
                            const int* __restrict__ offs, const int* __restrict__ rank,
                            int* __restrict__ csr_s, int E) {
    int i = blockIdx.x * blockDim.x + threadIdx.x;
    int st = gridDim.x * blockDim.x;
    for (; i < E; i += st) {
        int p = offs[dst[i]] + rank[i];
        csr_s[p] = src[i];
    }
}

// --------------------- precision-split conversions -------------------------
// x (fp32) -> hi/lo fp16, 8 elems per thread
__global__ void xsplit_kernel(const float* __restrict__ in, _Float16* __restrict__ hi,
                              _Float16* __restrict__ lo, int n8) {
    int i = blockIdx.x * blockDim.x + threadIdx.x;
    int st = gridDim.x * blockDim.x;
    const float4* in4 = (const float4*)in;
    for (; i < n8; i += st) {
        float4 v0 = in4[(size_t)i * 2];
        float4 v1 = in4[(size_t)i * 2 + 1];
        float v[8] = {v0.x, v0.y, v0.z, v0.w, v1.x, v1.y, v1.z, v1.w};
        half8 h, l;
#pragma unroll
        for (int j = 0; j < 8; ++j) {
            _Float16 hh = (_Float16)v[j];
            h[j] = hh;
            l[j] = (_Float16)(v[j] - (float)hh);
        }
        ((half8*)hi)[i] = h;
        ((half8*)lo)[i] = l;
    }
}

// W1,W2 (128x128), W3 (128x64) -> transposed WT[c][k] hi/lo fp16.
// layout: [0,16384) W1T, [16384,32768) W2T, [32768,40960) W3T
__global__ __launch_bounds__(256) void wsplit_kernel(const float* __restrict__ W1,
                                                     const float* __restrict__ W2,
                                                     const float* __restrict__ W3,
                                                     _Float16* __restrict__ hi,
                                                     _Float16* __restrict__ lo) {
    int idx = blockIdx.x * 256 + threadIdx.x;
    if (idx >= 40960) return;
    float v;
    if (idx < 16384) {
        int c = idx >> 7, k = idx & 127;
        v = W1[k * 128 + c];
    } else if (idx < 32768) {
        int j = idx - 16384;
        int c = j >> 7, k = j & 127;
        v = W2[k * 128 + c];
    } else {
        int j = idx - 32768;
        int c = j >> 7, k = j & 127;
        v = W3[k * 64 + c];
    }
    _Float16 h = (_Float16)v;
    hi[idx] = h;
    lo[idx] = (_Float16)(v - (float)h);
}

// ---------------------------------------------------------------------------
// MFMA GEMM: P[r][c] = sum_k X[r][k]*W[k][c], K=128, split-fp16 (3 mfma terms).
// No LDS. 256 thr = 4 waves; each wave: 32 rows (2 row-tiles) x NOUT cols.
// WT layout [c][k] => B-fragment is 16B contiguous. Epilogue: *dis[r], fp16.
// Fragment maps (16x16x32): A lane: row=l&15, k=8*(l>>4)+j. B lane: col=l&15,
// k=8*(l>>4)+j. C/D: col=l&15, row=(l>>4)*4+reg.
// ---------------------------------------------------------------------------
template <int NOUT>
__global__ __launch_bounds__(256) void gemm_mfma(const _Float16* __restrict__ Xhi,
                                                 const _Float16* __restrict__ Xlo,
                                                 const _Float16* __restrict__ WThi,
                                                 const _Float16* __restrict__ WTlo,
                                                 const float* __restrict__ dis,
                                                 _Float16* __restrict__ Y, int nrows) {
    constexpr int CT = NOUT / 16;
    const int wave = threadIdx.x >> 6;
    const int lane = threadIdx.x & 63;
    const int lrow = lane & 15;
    const int lk = lane >> 4;                       // 0..3
    const int r0 = (blockIdx.x * 4 + wave) * 32;    // 32 rows per wave

    const f32x4 Z = {0.f, 0.f, 0.f, 0.f};
    f32x4 acc[2][CT];
#pragma unroll
    for (int a = 0; a < 2; ++a)
#pragma unroll
        for (int b = 0; b < CT; ++b) acc[a][b] = Z;

    const half8* XhiV = (const half8*)Xhi;
    const half8* XloV = (const half8*)Xlo;
    const half8* WhiV = (const half8*)WThi;
    const half8* WloV = (const half8*)WTlo;

    int ar0 = r0 + lrow;
    int ar1 = r0 + 16 + lrow;
    if (ar0 > nrows - 1) ar0 = nrows - 1;
    if (ar1 > nrows - 1) ar1 = nrows - 1;

#pragma unroll
    for (int ks = 0; ks < 4; ++ks) {
        const int kidx = ks * 4 + lk;               // half8 index within a 128-row
        half8 a0h = XhiV[(size_t)ar0 * 16 + kidx];
        half8 a0l = XloV[(size_t)ar0 * 16 + kidx];
        half8 a1h = XhiV[(size_t)ar1 * 16 + kidx];
        half8 a1l = XloV[(size_t)ar1 * 16 + kidx];
#pragma unroll
        for (int ct = 0; ct < CT; ++ct) {
            const size_t bidx = (size_t)(ct * 16 + lrow) * 16 + kidx;
            half8 bh = WhiV[bidx];
            half8 bl = WloV[bidx];
            acc[0][ct] = __builtin_amdgcn_mfma_f32_16x16x32_f16(a0l, bh, acc[0][ct], 0, 0, 0);
            acc[0][ct] = __builtin_amdgcn_mfma_f32_16x16x32_f16(a0h, bl, acc[0][ct], 0, 0, 0);
            acc[0][ct] = __builtin_amdgcn_mfma_f32_16x16x32_f16(a0h, bh, acc[0][ct], 0, 0, 0);
            acc[1][ct] = __builtin_amdgcn_mfma_f32_16x16x32_f16(a1l, bh, acc[1][ct], 0, 0, 0);
            acc[1][ct] = __builtin_amdgcn_mfma_f32_16x16x32_f16(a1h, bl, acc[1][ct], 0, 0, 0);
            acc[1][ct] = __builtin_amdgcn_mfma_f32_16x16x32_f16(a1h, bh, acc[1][ct], 0, 0, 0);
        }
    }

    const int orow = r0 + lk * 4;
#pragma unroll
    for (int rt = 0; rt < 2; ++rt) {
#pragma unroll
        for (int r = 0; r < 4; ++r) {
            int row = orow + rt * 16 + r;
            if (row < nrows) {
                float dd = dis[row];
#pragma unroll
                for (int ct = 0; ct < CT; ++ct) {
                    Y[(size_t)row * NOUT + ct * 16 + lrow] =
                        (_Float16)(dd * acc[rt][ct][r]);
                }
            }
        }
    }
}

// ---------------------------------------------------------------------------
// Aggregation: ONE WAVE per node, 4 nodes per 256-thread block. No LDS.
// 8-deep unrolled gather pipeline; fp32 accumulate.
// out[d] = dis[d]*(sum_in h'[s] + h'[d]) + bias ; optional relu.
// SPLIT=true: store hi/lo fp16 (next GEMM input). SPLIT=false: fp32 out.
// ---------------------------------------------------------------------------
template <int F, bool RELU, bool SPLIT>
__global__ __launch_bounds__(256) void agg_kernel(const __half* __restrict__ h,
                                                  const float* __restrict__ dis,
                                                  const int* __restrict__ offs,
                                                  const int* __restrict__ csr_s,
                                                  const float* __restrict__ bias,
                                                  float* __restrict__ outf,
                                                  __half* __restrict__ ohi,
                                                  __half* __restrict__ olo, int n) {
    const int d = blockIdx.x * 4 + (threadIdx.x >> 6);
    if (d >= n) return;
    const int lane = threadIdx.x & 63;
    const int beg = offs[d];
    const int end = offs[d + 1];

    float sx = 0.f, sy = 0.f;
    int i = beg;
    if constexpr (F == 128) {
        const unsigned* h32 = (const unsigned*)h;
        for (; i + 8 <= end; i += 8) {
            int s[8];
#pragma unroll
            for (int j = 0; j < 8; ++j) s[j] = csr_s[i + j];
            unsigned v[8];
#pragma unroll
            for (int j = 0; j < 8; ++j) v[j] = h32[(size_t)s[j] * 64 + lane];
#pragma unroll
            for (int j = 0; j < 8; ++j) {
                float2 vf = __half22float2(*reinterpret_cast<__half2*>(&v[j]));
                sx += vf.x;
                sy += vf.y;
            }
        }
        if (i + 4 <= end) {
            int s[4];
#pragma unroll
            for (int j = 0; j < 4; ++j) s[j] = csr_s[i + j];
            unsigned v[4];
#pragma unroll
            for (int j = 0; j < 4; ++j) v[j] = h32[(size_t)s[j] * 64 + lane];
#pragma unroll
            for (int j = 0; j < 4; ++j) {
                float2 vf = __half22float2(*reinterpret_cast<__half2*>(&v[j]));
                sx += vf.x;
                sy += vf.y;
            }
            i += 4;
        }
        for (; i < end; ++i) {
            unsigned v = h32[(size_t)csr_s[i] * 64 + lane];
            float2 vf = __half22float2(*reinterpret_cast<__half2*>(&v));
            sx += vf.x;
            sy += vf.y;
        }
        {   // self row
            unsigned v = h32[(size_t)d * 64 + lane];
            float2 vf = __half22float2(*reinterpret_cast<__half2*>(&v));
            sx += vf.x;
            sy += vf.y;
        }
        float dd = dis[d];
        float2 b2 = ((const float2*)bias)[lane];
        float rx = fmaf(dd, sx, b2.x);
        float ry = fmaf(dd, sy, b2.y);
        if (RELU) {
            rx = fmaxf(rx, 0.f);
            ry = fmaxf(ry, 0.f);
        }
        if constexpr (SPLIT) {
            __half hx = __float2half(rx), hy = __float2half(ry);
            __half lx = __float2half(rx - __half2float(hx));
            __half ly = __float2half(ry - __half2float(hy));
            ((__half2*)(ohi + (size_t)d * F))[lane] = __halves2half2(hx, hy);
            ((__half2*)(olo + (size_t)d * F))[lane] = __halves2half2(lx, ly);
        } else {
            ((float2*)(outf + (size_t)d * F))[lane] = make_float2(rx, ry);
        }
    } else {
        const unsigned short* h16 = (const unsigned short*)h;
        for (; i + 8 <= end; i += 8) {
            int s[8];
#pragma unroll
            for (int j = 0; j < 8; ++j) s[j] = csr_s[i + j];
            unsigned short v[8];
#pragma unroll
            for (int j = 0; j < 8; ++j) v[j] = h16[(size_t)s[j] * 64 + lane];
#pragma unroll
            for (int j = 0; j < 8; ++j)
                sx += __half2float(*reinterpret_cast<__half*>(&v[j]));
        }
        if (i + 4 <= end) {
            int s[4];
#pragma unroll
            for (int j = 0; j < 4; ++j) s[j] = csr_s[i + j];
            unsigned short v[4];
#pragma unroll
            for (int j = 0; j < 4; ++j) v[j] = h16[(size_t)s[j] * 64 + lane];
#pragma unroll
            for (int j = 0; j < 4; ++j)
                sx += __half2float(*reinterpret_cast<__half*>(&v[j]));
            i += 4;
        }
        for (; i < end; ++i) {
            unsigned short v = h16[(size_t)csr_s[i] * 64 + lane];
            sx += __half2float(*reinterpret_cast<__half*>(&v));
        }
        {
            unsigned short v = h16[(size_t)d * 64 + lane];
            sx += __half2float(*reinterpret_cast<__half*>(&v));
        }
        float dd = dis[d];
        float r = fmaf(dd, sx, bias[lane]);
        if (RELU) r = fmaxf(r, 0.f);
        out_store:
        if constexpr (SPLIT) {
            __half hx = __float2half(r);
            ohi[(size_t)d * F + lane] = hx;
            olo[(size_t)d * F + lane] = __float2half(r - __half2float(hx));
        } else {
            outf[(size_t)d * F + lane] = r;
        }
    }
}

// ---------------------------------------------------------------------------

extern "C" void kernel_launch(void* const* d_in, const int* in_sizes, int n_in,
                              void* d_out, int out_size, void* d_ws, size_t ws_size,
                              hipStream_t stream) {
    const float* x  = (const float*)d_in[0];
    const int*   ei = (const int*)d_in[1];
    const float* W1 = (const float*)d_in[2];
    const float* b1 = (const float*)d_in[3];
    const float* W2 = (const float*)d_in[4];
    const float* b2 = (const float*)d_in[5];
    const float* W3 = (const float*)d_in[6];
    const float* b3 = (const float*)d_in[7];

    const int N = in_sizes[0] / 128;
    const int E = in_sizes[1] / 2;
    const int* src = ei;
    const int* dst = ei + E;
    float* out = (float*)d_out;

    char* w = (char*)d_ws;
    auto take = [&](size_t bytes) -> void* {
        void* p = (void*)w;
        w += (bytes + 255) & ~(size_t)255;
        return p;
    };
    int*      counts = (int*)take((size_t)N * 4);
    int*      offs   = (int*)take((size_t)(N + 1) * 4);
    float*    dis    = (float*)take((size_t)N * 4);
    int*      bsum   = (int*)take((size_t)1024 * 4);
    int*      csr_s  = (int*)take((size_t)E * 4);
    _Float16* G16    = (_Float16*)take((size_t)N * 128 * 2);  // prescaled fp16 rows
    _Float16* Xhi    = (_Float16*)take((size_t)N * 128 * 2);  // GEMM input hi
    _Float16* Xlo    = (_Float16*)take((size_t)N * 128 * 2);  // GEMM input lo
    _Float16* Whi    = (_Float16*)take((size_t)40960 * 2);
    _Float16* Wlo    = (_Float16*)take((size_t)40960 * 2);
    // rank is only live between count_kernel and fill_kernel; G16 is only
    // written from the first GEMM onward (same stream => sequential). Alias.
    int*      rank   = (int*)G16;

    const int NBLK = (N + 256) / 256;

    // --- graph preprocessing ---
    hipMemsetAsync(counts, 0, (size_t)N * 4, stream);
    count_kernel<<<2048, 256, 0, stream>>>(dst, counts, rank, E);
    block_sum_kernel<<<NBLK, 256, 0, stream>>>(counts, bsum, N);
    small_scan_kernel<<<1, 256, 0, stream>>>(bsum, NBLK);
    scan_block_kernel<<<NBLK, 256, 0, stream>>>(counts, bsum, offs, dis, N, E);
    fill_kernel<<<2048, 256, 0, stream>>>(src, dst, offs, rank, csr_s, E);

    // --- precision splits ---
    wsplit_kernel<<<160, 256, 0, stream>>>(W1, W2, W3, Whi, Wlo);
    xsplit_kernel<<<2048, 256, 0, stream>>>(x, Xhi, Xlo, N * 16);

    const int gblocks = (N + 127) / 128;   // 128 rows per block (4 waves x 32)
    const int ablocks = (N + 3) / 4;

    // layer 1
    gemm_mfma<128><<<gblocks, 256, 0, stream>>>(Xhi, Xlo, Whi, Wlo, dis, G16, N);
    agg_kernel<128, true, true><<<ablocks, 256, 0, stream>>>(
        (const __half*)G16, dis, offs, csr_s, b1, nullptr, (__half*)Xhi, (__half*)Xlo, N);
    // layer 2
    gemm_mfma<128><<<gblocks, 256, 0, stream>>>(Xhi, Xlo, Whi + 16384, Wlo + 16384,
                                                dis, G16, N);
    agg_kernel<128, true, true><<<ablocks, 256, 0, stream>>>(
        (const __half*)G16, dis, offs, csr_s, b2, nullptr, (__half*)Xhi, (__half*)Xlo, N);
    // layer 3
    gemm_mfma<64><<<gblocks, 256, 0, stream>>>(Xhi, Xlo, Whi + 32768, Wlo + 32768,
                                               dis, G16, N);
    agg_kernel<64, false, false><<<ablocks, 256, 0, stream>>>(
        (const __half*)G16, dis, offs, csr_s, b3, out, nullptr, nullptr, N);
}